// Round 1
// baseline (504.389 us; speedup 1.0000x reference)
//
#include <hip/hip_runtime.h>

#define N_VOX 100000
#define K_OFF 27
#define M_PAIR 60000
#define CIN 64
#define COUT 64
#define BN_EPS 1e-5f

// One wave per (k, m) pair (grid-strided over m). W[k] column held in VGPRs,
// feats row fetched via scalar loads (wave-uniform row index), one coalesced
// 64-lane atomicAdd per pair into the fp32 accumulator (d_out).
__global__ __launch_bounds__(256) void sparse_conv_kernel(
    const float* __restrict__ feats, const float* __restrict__ W,
    const int* __restrict__ in_idx, const int* __restrict__ out_idx,
    float* __restrict__ out)
{
    const int k = blockIdx.y;
    const int lane = threadIdx.x & 63;
    const int wave_in_block = threadIdx.x >> 6;
    const int waves_per_block = blockDim.x >> 6;
    const int wave = blockIdx.x * waves_per_block + wave_in_block;
    const int num_waves = gridDim.x * waves_per_block;

    // Preload W[k][:, lane] (a full column per lane) into 64 VGPRs.
    // Coalesced across lanes for each i (W[k][i][*] is contiguous).
    float w[CIN];
    const float* __restrict__ Wk = W + k * CIN * COUT;
#pragma unroll
    for (int i = 0; i < CIN; ++i) w[i] = Wk[i * COUT + lane];

    const int base = k * M_PAIR;
    for (int m = wave; m < M_PAIR; m += num_waves) {
        // Force wave-uniform row indices -> SGPRs -> feats row via s_load.
        const int row_in  = __builtin_amdgcn_readfirstlane(in_idx[base + m]);
        const int row_out = __builtin_amdgcn_readfirstlane(out_idx[base + m]);
        const float* __restrict__ f = feats + row_in * CIN;

        // 4-way split accumulators to break the serial FMA dependence chain.
        float a0 = 0.f, a1 = 0.f, a2 = 0.f, a3 = 0.f;
#pragma unroll
        for (int i = 0; i < CIN; i += 4) {
            a0 = fmaf(f[i + 0], w[i + 0], a0);
            a1 = fmaf(f[i + 1], w[i + 1], a1);
            a2 = fmaf(f[i + 2], w[i + 2], a2);
            a3 = fmaf(f[i + 3], w[i + 3], a3);
        }
        const float acc = (a0 + a1) + (a2 + a3);
        atomicAdd(&out[row_out * COUT + lane], acc);
    }
}

// In-place BatchNorm (inference, running stats) + ReLU over [N_VOX, COUT].
__global__ __launch_bounds__(256) void bn_relu_kernel(
    float* __restrict__ out,
    const float* __restrict__ gamma, const float* __restrict__ beta,
    const float* __restrict__ mean, const float* __restrict__ var)
{
    const int e = blockIdx.x * blockDim.x + threadIdx.x;
    if (e >= N_VOX * COUT) return;
    const int c = e & (COUT - 1);
    const float inv = rsqrtf(var[c] + BN_EPS);
    const float y = (out[e] - mean[c]) * (inv * gamma[c]) + beta[c];
    out[e] = fmaxf(y, 0.f);
}

extern "C" void kernel_launch(void* const* d_in, const int* in_sizes, int n_in,
                              void* d_out, int out_size, void* d_ws, size_t ws_size,
                              hipStream_t stream) {
    const float* feats = (const float*)d_in[0];
    const float* W     = (const float*)d_in[1];
    const float* gamma = (const float*)d_in[2];
    const float* beta  = (const float*)d_in[3];
    const float* rmean = (const float*)d_in[4];
    const float* rvar  = (const float*)d_in[5];
    const int* in_idx  = (const int*)d_in[6];
    const int* out_idx = (const int*)d_in[7];
    float* out = (float*)d_out;

    // Zero the accumulator (d_out is poisoned 0xAA before every launch).
    hipMemsetAsync(out, 0, (size_t)N_VOX * COUT * sizeof(float), stream);

    // Conv: blockIdx.y = kernel offset; 4 waves/block; ~472 waves per k
    // (~12 waves/SIMD total oversubscription, ~127 pairs per wave so the
    // 64-VGPR W[k] preload is well amortized).
    dim3 grid(118, K_OFF, 1);
    dim3 block(256, 1, 1);
    sparse_conv_kernel<<<grid, block, 0, stream>>>(feats, W, in_idx, out_idx, out);

    // BN + ReLU in place.
    const int total = N_VOX * COUT;
    bn_relu_kernel<<<(total + 255) / 256, 256, 0, stream>>>(out, gamma, beta, rmean, rvar);
}

// Round 3
// 444.208 us; speedup vs baseline: 1.1355x; 1.1355x over previous
//
#include <hip/hip_runtime.h>

#define N_VOX 100000
#define K_OFF 27
#define M_PAIR 60000
#define CIN 64
#define COUT 64
#define BN_EPS 1e-5f

typedef __attribute__((ext_vector_type(8))) short bf16x8;
typedef __attribute__((ext_vector_type(4))) float f32x4;

// fp32 -> bf16 (round-to-nearest-even), raw ushort. Data is well-behaved
// (no NaN), so skip the NaN special case.
__device__ __forceinline__ unsigned short f32_to_bf16(float f) {
    unsigned int u = __float_as_uint(f);
    u += 0x7FFFu + ((u >> 16) & 1u);
    return (unsigned short)(u >> 16);
}

// ws layout: [0, 12.8MB) feats_bf16 [N_VOX][64]; then Wt bf16 [27][c=64][i=64]
#define WS_FB_ELEMS (N_VOX * CIN)

// Convert feats fp32 -> bf16 (float4-wide) and zero the fp32 accumulator.
__global__ __launch_bounds__(256) void prep_feats_kernel(
    const float* __restrict__ feats, unsigned short* __restrict__ fb,
    float* __restrict__ out)
{
    const int e = blockIdx.x * blockDim.x + threadIdx.x;   // x4 elems each
    const int e4 = e * 4;
    if (e4 >= N_VOX * CIN) return;
    const float4 v = *(const float4*)(feats + e4);
    ushort4 b;
    b.x = f32_to_bf16(v.x);
    b.y = f32_to_bf16(v.y);
    b.z = f32_to_bf16(v.z);
    b.w = f32_to_bf16(v.w);
    *(ushort4*)(fb + e4) = b;
    *(float4*)(out + e4) = make_float4(0.f, 0.f, 0.f, 0.f);
}

// Transpose W[k][i][c] fp32 -> Wt[k][c][i] bf16 (tiny: 110592 elems).
__global__ __launch_bounds__(256) void prep_w_kernel(
    const float* __restrict__ W, unsigned short* __restrict__ Wt)
{
    const int e = blockIdx.x * blockDim.x + threadIdx.x;
    if (e >= K_OFF * CIN * COUT) return;
    const int k = e / (CIN * COUT);
    const int r = e % (CIN * COUT);
    const int i = r / COUT;
    const int c = r % COUT;
    Wt[k * CIN * COUT + c * CIN + i] = f32_to_bf16(W[e]);
}

// One wave per 16 (in,out) pairs: gather A rows, 8x mfma_f32_16x16x32_bf16
// (Cin=64 in two K-halves x 4 cout-tiles), scatter-atomic per C/D layout.
__global__ __launch_bounds__(256) void conv_mfma_kernel(
    const unsigned short* __restrict__ fb, const unsigned short* __restrict__ Wt,
    const int* __restrict__ in_idx, const int* __restrict__ out_idx,
    float* __restrict__ out)
{
    const int k = blockIdx.y;
    const int lane = threadIdx.x & 63;
    const int wave = blockIdx.x * 4 + (threadIdx.x >> 6);  // 0..127 per k
    const int col = lane & 15;
    const int quad = lane >> 4;

    // B fragments: B[kk][n] with n=lane&15, kk=quad*8+j. Wt[k][c][i] makes the
    // 8 j-elements contiguous. 4 cout-tiles x 2 K-halves = 32 VGPRs.
    bf16x8 Bf[4][2];
    const short* Wk = (const short*)(Wt + k * CIN * COUT);
#pragma unroll
    for (int t = 0; t < 4; ++t) {
        const short* p = Wk + (t * 16 + col) * CIN + quad * 8;
        Bf[t][0] = *(const bf16x8*)(p);
        Bf[t][1] = *(const bf16x8*)(p + 32);
    }

    const int base = k * M_PAIR;
    const int ntiles = M_PAIR / 16;                        // 3750
    for (int tile = wave; tile < ntiles; tile += 128) {
        const int m0 = base + tile * 16;
        // A fragment: A[m=col][kk=quad*8+j]; row = in_idx of pair m0+col.
        const int rin = in_idx[m0 + col];
        const short* fp = (const short*)fb + (size_t)rin * CIN + quad * 8;
        const bf16x8 A0 = *(const bf16x8*)(fp);
        const bf16x8 A1 = *(const bf16x8*)(fp + 32);

        f32x4 acc[4];
#pragma unroll
        for (int t = 0; t < 4; ++t) {
            f32x4 z = {0.f, 0.f, 0.f, 0.f};
            acc[t] = __builtin_amdgcn_mfma_f32_16x16x32_bf16(A0, Bf[t][0], z, 0, 0, 0);
            acc[t] = __builtin_amdgcn_mfma_f32_16x16x32_bf16(A1, Bf[t][1], acc[t], 0, 0, 0);
        }

        // C/D layout: cout = t*16 + col, pair m_local = quad*4 + r.
        int vo[4];
#pragma unroll
        for (int r = 0; r < 4; ++r) vo[r] = out_idx[m0 + quad * 4 + r];
#pragma unroll
        for (int r = 0; r < 4; ++r) {
            float* op = out + (size_t)vo[r] * COUT + col;
#pragma unroll
            for (int t = 0; t < 4; ++t) atomicAdd(op + t * 16, acc[t][r]);
        }
    }
}

// In-place BatchNorm (inference) + ReLU over [N_VOX, COUT].
__global__ __launch_bounds__(256) void bn_relu_kernel(
    float* __restrict__ out,
    const float* __restrict__ gamma, const float* __restrict__ beta,
    const float* __restrict__ mean, const float* __restrict__ var)
{
    const int e = blockIdx.x * blockDim.x + threadIdx.x;
    if (e >= N_VOX * COUT) return;
    const int c = e & (COUT - 1);
    const float inv = rsqrtf(var[c] + BN_EPS);
    const float y = (out[e] - mean[c]) * (inv * gamma[c]) + beta[c];
    out[e] = fmaxf(y, 0.f);
}

extern "C" void kernel_launch(void* const* d_in, const int* in_sizes, int n_in,
                              void* d_out, int out_size, void* d_ws, size_t ws_size,
                              hipStream_t stream) {
    const float* feats = (const float*)d_in[0];
    const float* W     = (const float*)d_in[1];
    const float* gamma = (const float*)d_in[2];
    const float* beta  = (const float*)d_in[3];
    const float* rmean = (const float*)d_in[4];
    const float* rvar  = (const float*)d_in[5];
    const int* in_idx  = (const int*)d_in[6];
    const int* out_idx = (const int*)d_in[7];
    float* out = (float*)d_out;

    unsigned short* fb = (unsigned short*)d_ws;
    unsigned short* Wt = (unsigned short*)((char*)d_ws + (size_t)WS_FB_ELEMS * 2);

    // Prep: feats->bf16 + zero accumulator; W->bf16 transposed.
    const int n_vec4 = (N_VOX * CIN) / 4;
    prep_feats_kernel<<<(n_vec4 + 255) / 256, 256, 0, stream>>>(feats, fb, out);
    const int wtot = K_OFF * CIN * COUT;
    prep_w_kernel<<<(wtot + 255) / 256, 256, 0, stream>>>(W, Wt);

    // Conv: 27 x 32 blocks x 4 waves = 128 waves/k, ~29 tiles each.
    dim3 grid(32, K_OFF, 1);
    conv_mfma_kernel<<<grid, dim3(256, 1, 1), 0, stream>>>(fb, Wt, in_idx, out_idx, out);

    // BN + ReLU in place.
    const int total = N_VOX * COUT;
    bn_relu_kernel<<<(total + 255) / 256, 256, 0, stream>>>(out, gamma, beta, rmean, rvar);
}